// Round 3
// baseline (119.220 us; speedup 1.0000x reference)
//
#include <hip/hip_runtime.h>
#include <hip/hip_fp16.h>

#define N_AG 512
#define TRAJ 16
#define TAU_ 2048
#define MSG_ 32768
#define HID_ 512
#define DV_ 64
#define SPLITQ 32
#define LDS_K 40            // 32 k-halves + 8 pad -> 80B row stride (16B-aligned rows)
#define BUFH (128 * LDS_K)  // halves per LDS buffer side (qgemm, 128-row tiles)
#define BUF64 (64 * LDS_K)  // halves per LDS buffer side (kvgemm, 64-row tiles)

typedef _Float16 f16x8 __attribute__((ext_vector_type(8)));
typedef _Float16 f16x4 __attribute__((ext_vector_type(4)));
typedef _Float16 f16x2 __attribute__((ext_vector_type(2)));
typedef float f32x4 __attribute__((ext_vector_type(4)));

// ---------------- qgemm tile: 128x128, BK=32, 4 waves (2x2) ----------------
// A [128 x K] row-major fp32, B [K x 128] row-major fp32, C fp16.
// fp32->fp16 cast fused into LDS staging; 2-buf LDS + 2 reg stage buffers.
__device__ __forceinline__ void gemm_tile128(
    _Float16* __restrict__ As, _Float16* __restrict__ Bs,
    const float* __restrict__ Ag, int lda,
    const float* __restrict__ Bg, int ldb,
    _Float16* __restrict__ Cg, int ldc, int K)
{
    const int tid = threadIdx.x;
    const int lane = tid & 63;
    const int wid = tid >> 6;
    const int wr = wid >> 1;
    const int wc = wid & 1;

    const int am = tid >> 1;             // row 0..127
    const int ak = (tid & 1) << 4;       // 0 or 16
    const int btn = tid & 31;            // col-quad
    const int btk = tid >> 5;            // k-quad

    const int arow = wr * 64 + (lane & 15);
    const int brow = wc * 64 + (lane & 15);
    const int kblk = (lane >> 4) << 3;

    f32x4 acc[4][4];
#pragma unroll
    for (int mi = 0; mi < 4; ++mi)
#pragma unroll
        for (int ni = 0; ni < 4; ++ni)
            acc[mi][ni] = (f32x4){0.f, 0.f, 0.f, 0.f};

    float4 rA[8], rB[8];
    const int nt = K >> 5;

    auto load_stage = [&](float4 (&r)[8], int ks) {
        const float* ap = Ag + (size_t)am * lda + ks + ak;
#pragma unroll
        for (int i = 0; i < 4; ++i)
            r[i] = *(const float4*)(ap + 4 * i);
        const float* bp = Bg + (size_t)(ks + btk * 4) * ldb + btn * 4;
#pragma unroll
        for (int i = 0; i < 4; ++i)
            r[4 + i] = *(const float4*)(bp + (size_t)i * ldb);
    };

    auto write_stage = [&](float4 (&r)[8], int buf) {
        _Float16* abase = As + buf * BUFH + am * LDS_K + ak;
        const float* fa = (const float*)&r[0];
        f16x8 h0, h1;
#pragma unroll
        for (int i = 0; i < 8; ++i) { h0[i] = (_Float16)fa[i]; h1[i] = (_Float16)fa[8 + i]; }
        *(f16x8*)abase = h0;
        *(f16x8*)(abase + 8) = h1;
        const float* fb = (const float*)&r[4];
#pragma unroll
        for (int j = 0; j < 4; ++j) {
            f16x4 w;
#pragma unroll
            for (int i = 0; i < 4; ++i) w[i] = (_Float16)fb[i * 4 + j];
            *(f16x4*)(Bs + buf * BUFH + (btn * 4 + j) * LDS_K + btk * 4) = w;
        }
    };

    auto compute = [&](int buf) {
        const _Float16* ab = As + buf * BUFH;
        const _Float16* bb = Bs + buf * BUFH;
        f16x8 af[4], bf[4];
#pragma unroll
        for (int mi = 0; mi < 4; ++mi)
            af[mi] = *(const f16x8*)(ab + (arow + mi * 16) * LDS_K + kblk);
#pragma unroll
        for (int ni = 0; ni < 4; ++ni)
            bf[ni] = *(const f16x8*)(bb + (brow + ni * 16) * LDS_K + kblk);
#pragma unroll
        for (int mi = 0; mi < 4; ++mi)
#pragma unroll
            for (int ni = 0; ni < 4; ++ni)
                acc[mi][ni] = __builtin_amdgcn_mfma_f32_16x16x32_f16(
                    af[mi], bf[ni], acc[mi][ni], 0, 0, 0);
    };

    load_stage(rA, 0);
    load_stage(rB, 32);
    write_stage(rA, 0);
    __syncthreads();

    for (int t = 0; t < nt; t += 2) {
        if (t + 2 < nt) load_stage(rA, (t + 2) << 5);
        compute(0);
        if (t + 1 < nt) write_stage(rB, 1);
        __syncthreads();
        if (t + 3 < nt) load_stage(rB, (t + 3) << 5);
        compute(1);
        if (t + 2 < nt) write_stage(rA, 0);
        __syncthreads();
    }

    // C/D layout (HW-verified): col = lane&15, row = (lane>>4)*4 + reg
#pragma unroll
    for (int mi = 0; mi < 4; ++mi) {
#pragma unroll
        for (int ni = 0; ni < 4; ++ni) {
            const int row = wr * 64 + mi * 16 + ((lane >> 4) << 2);
            const int col = wc * 64 + ni * 16 + (lane & 15);
#pragma unroll
            for (int r = 0; r < 4; ++r)
                Cg[(size_t)(row + r) * ldc + col] = (_Float16)acc[mi][ni][r];
        }
    }
}

// ---------------- kv tile: 64x64, BK=32, 4 waves (2x2) ----------------
// Small tile -> 20KB LDS -> 4-5 blocks/CU for latency hiding via TLP.
__device__ __forceinline__ void gemm64(
    _Float16* __restrict__ As, _Float16* __restrict__ Bs,
    const float* __restrict__ Ag, int lda,
    const float* __restrict__ Bg, int ldb,
    _Float16* __restrict__ Cg, int ldc,
    const float* __restrict__ bias, int K)
{
    const int tid = threadIdx.x;
    const int lane = tid & 63;
    const int wid = tid >> 6;
    const int wr = wid >> 1;
    const int wc = wid & 1;

    const int am = tid >> 2;             // row 0..63
    const int ak = (tid & 3) << 3;       // 0,8,16,24
    const int btn = tid & 15;            // col-quad 0..15
    const int btk = tid >> 4;            // 0..15, 2 k-rows each

    const int arow = wr * 32 + (lane & 15);
    const int brow = wc * 32 + (lane & 15);
    const int kblk = (lane >> 4) << 3;

    f32x4 acc[2][2];
#pragma unroll
    for (int mi = 0; mi < 2; ++mi)
#pragma unroll
        for (int ni = 0; ni < 2; ++ni)
            acc[mi][ni] = (f32x4){0.f, 0.f, 0.f, 0.f};

    float4 rA[4], rB[4];  // [0..1] A (8 floats), [2..3] B (2 rows x 4 cols)
    const int nt = K >> 5;

    auto load_stage = [&](float4 (&r)[4], int ks) {
        const float* ap = Ag + (size_t)am * lda + ks + ak;
        r[0] = *(const float4*)(ap);
        r[1] = *(const float4*)(ap + 4);
        const float* bp = Bg + (size_t)(ks + btk * 2) * ldb + btn * 4;
        r[2] = *(const float4*)(bp);
        r[3] = *(const float4*)(bp + ldb);
    };

    auto write_stage = [&](float4 (&r)[4], int buf) {
        const float* fa = (const float*)&r[0];
        f16x8 h;
#pragma unroll
        for (int i = 0; i < 8; ++i) h[i] = (_Float16)fa[i];
        *(f16x8*)(As + buf * BUF64 + am * LDS_K + ak) = h;
        const float* fb = (const float*)&r[2];
#pragma unroll
        for (int c = 0; c < 4; ++c) {
            f16x2 w;
            w[0] = (_Float16)fb[c];
            w[1] = (_Float16)fb[4 + c];
            *(f16x2*)(Bs + buf * BUF64 + (btn * 4 + c) * LDS_K + btk * 2) = w;
        }
    };

    auto compute = [&](int buf) {
        const _Float16* ab = As + buf * BUF64;
        const _Float16* bb = Bs + buf * BUF64;
        f16x8 af[2], bf[2];
#pragma unroll
        for (int mi = 0; mi < 2; ++mi)
            af[mi] = *(const f16x8*)(ab + (arow + mi * 16) * LDS_K + kblk);
#pragma unroll
        for (int ni = 0; ni < 2; ++ni)
            bf[ni] = *(const f16x8*)(bb + (brow + ni * 16) * LDS_K + kblk);
#pragma unroll
        for (int mi = 0; mi < 2; ++mi)
#pragma unroll
            for (int ni = 0; ni < 2; ++ni)
                acc[mi][ni] = __builtin_amdgcn_mfma_f32_16x16x32_f16(
                    af[mi], bf[ni], acc[mi][ni], 0, 0, 0);
    };

    load_stage(rA, 0);
    load_stage(rB, 32);
    write_stage(rA, 0);
    __syncthreads();

    for (int t = 0; t < nt; t += 2) {
        if (t + 2 < nt) load_stage(rA, (t + 2) << 5);
        compute(0);
        if (t + 1 < nt) write_stage(rB, 1);
        __syncthreads();
        if (t + 3 < nt) load_stage(rB, (t + 3) << 5);
        compute(1);
        if (t + 2 < nt) write_stage(rA, 0);
        __syncthreads();
    }

#pragma unroll
    for (int mi = 0; mi < 2; ++mi) {
#pragma unroll
        for (int ni = 0; ni < 2; ++ni) {
            const int row = wr * 32 + mi * 16 + ((lane >> 4) << 2);
            const int col = wc * 32 + ni * 16 + (lane & 15);
            const float badd = bias[col];
#pragma unroll
            for (int r = 0; r < 4; ++r)
                Cg[(size_t)(row + r) * ldc + col] = (_Float16)(acc[mi][ni][r] + badd);
        }
    }
}

// q partials: split-K=32 (1024 each), grid 512 blocks (2/CU), XCD-chunked.
__global__ __launch_bounds__(256, 2) void qgemm(const float* __restrict__ X,
                                                const float* __restrict__ Wq,
                                                _Float16* __restrict__ qpart)
{
    __shared__ __align__(16) _Float16 smem[4 * BUFH];
    const int b = blockIdx.x;
    const int w = (b & 7) * 64 + (b >> 3);
    const int s = w >> 4;
    const int bm = (w >> 2) & 3;
    const int bn = w & 3;
    const int KS = MSG_ / SPLITQ;  // 1024
    gemm_tile128(smem, smem + 2 * BUFH,
                 X + (size_t)bm * 128 * MSG_ + s * KS, MSG_,
                 Wq + (size_t)(s * KS) * HID_ + bn * 128, HID_,
                 qpart + (size_t)s * (N_AG * HID_) + bm * 128 * HID_ + bn * 128, HID_,
                 KS);
}

// k (bn 0..7, 64-col slices of Wk) and v (bn==8): 64x64 tiles, grid 128x9=1152.
__global__ __launch_bounds__(256, 4) void kvgemm(const float* __restrict__ Tr,
                                                 const float* __restrict__ Wk,
                                                 const float* __restrict__ bk,
                                                 const float* __restrict__ Wv,
                                                 const float* __restrict__ bv,
                                                 _Float16* __restrict__ kout,
                                                 _Float16* __restrict__ vout)
{
    __shared__ __align__(16) _Float16 smem[4 * BUF64];
    const int b = blockIdx.x;
    const int w = (b & 7) * 144 + (b >> 3);  // 1152 = 8 XCD chunks of 144
    const int bm = w / 9;
    const int bn = w % 9;
    const float* Ag = Tr + (size_t)bm * 64 * TAU_;
    if (bn < 8) {
        gemm64(smem, smem + 2 * BUF64, Ag, TAU_,
               Wk + bn * 64, HID_,
               kout + (size_t)bm * 64 * HID_ + bn * 64, HID_,
               bk + bn * 64, TAU_);
    } else {
        gemm64(smem, smem + 2 * BUF64, Ag, TAU_,
               Wv, DV_,
               vout + (size_t)bm * 64 * DV_, DV_,
               bv, TAU_);
    }
}

// Per-agent: reduce fp16 q-partials (+bq), 16 dots via shuffle-reduce, softmax, PV.
__global__ __launch_bounds__(256) void attn(const _Float16* __restrict__ qpart,
                                            const _Float16* __restrict__ kmat,
                                            const _Float16* __restrict__ vmat,
                                            const float* __restrict__ bq,
                                            const float* __restrict__ bv,
                                            float* __restrict__ out)
{
    const int n = blockIdx.x;
    const int tid = threadIdx.x;
    __shared__ float qs[HID_];
    __shared__ float scr[TRAJ];

    {
        const int h2 = tid * 2;
        float a0 = bq[h2], a1 = bq[h2 + 1];
#pragma unroll
        for (int s = 0; s < SPLITQ; ++s) {
            f16x2 p = *(const f16x2*)(qpart + (size_t)s * (N_AG * HID_) + n * HID_ + h2);
            a0 += (float)p[0];
            a1 += (float)p[1];
        }
        qs[h2] = a0;
        qs[h2 + 1] = a1;
    }
    __syncthreads();

    const int w = tid >> 6;
    const int lane = tid & 63;
#pragma unroll
    for (int tt = 0; tt < 4; ++tt) {
        const int t = w * 4 + tt;
        const _Float16* kr = kmat + (size_t)(t * N_AG + n) * HID_;
        const int h0 = lane * 8;
        f16x8 kv = *(const f16x8*)(kr + h0);
        float p = 0.f;
#pragma unroll
        for (int i = 0; i < 8; ++i)
            p += qs[h0 + i] * (float)kv[i];
#pragma unroll
        for (int off = 32; off > 0; off >>= 1)
            p += __shfl_xor(p, off);
        if (lane == 0) scr[t] = p;
    }
    __syncthreads();

    const float inv = 0.04419417382415922f;  // 1/sqrt(512)
    float sv[TRAJ];
    float mx = -1e30f;
#pragma unroll
    for (int t = 0; t < TRAJ; ++t) { sv[t] = scr[t] * inv; mx = fmaxf(mx, sv[t]); }
    float ssum = 0.f;
#pragma unroll
    for (int t = 0; t < TRAJ; ++t) { sv[t] = expf(sv[t] - mx); ssum += sv[t]; }
    const float rs = 1.f / ssum;

    if (tid < DV_) {
        float o = bv[tid];
#pragma unroll
        for (int t = 0; t < TRAJ; ++t)
            o += sv[t] * rs * (float)vmat[(size_t)(t * N_AG + n) * DV_ + tid];
        out[n * DV_ + tid] = o;
    }
}

extern "C" void kernel_launch(void* const* d_in, const int* in_sizes, int n_in,
                              void* d_out, int out_size, void* d_ws, size_t ws_size,
                              hipStream_t stream)
{
    const float* traj = (const float*)d_in[0];  // [16,512,2048] == taus [8192,2048]
    const float* msgs = (const float*)d_in[1];  // [512, 32768]
    const float* Wq   = (const float*)d_in[2];  // [32768, 512]
    const float* bq   = (const float*)d_in[3];  // [512]
    const float* Wk   = (const float*)d_in[4];  // [2048, 512]
    const float* bk   = (const float*)d_in[5];  // [512]
    const float* Wv   = (const float*)d_in[6];  // [2048, 64]
    const float* bv   = (const float*)d_in[7];  // [64]
    float* out = (float*)d_out;                 // [512, 64]

    // ws (fp16): qpart [32][512][512] 16MB | k [8192][512] 8MB | v [8192][64] 1MB
    _Float16* qpart = (_Float16*)d_ws;
    _Float16* kmat = qpart + (size_t)SPLITQ * N_AG * HID_;
    _Float16* vmat = kmat + (size_t)TRAJ * N_AG * HID_;

    qgemm<<<512, 256, 0, stream>>>(msgs, Wq, qpart);
    kvgemm<<<1152, 256, 0, stream>>>(traj, Wk, bk, Wv, bv, kmat, vmat);
    attn<<<512, 256, 0, stream>>>(qpart, kmat, vmat, bq, bv, out);
}

// Round 5
// 95.779 us; speedup vs baseline: 1.2447x; 1.2447x over previous
//
#include <hip/hip_runtime.h>
#include <hip/hip_fp16.h>

#define N_AG 512
#define TRAJ 16
#define TAU_ 2048
#define MSG_ 32768
#define HID_ 512
#define DV_ 64
#define NTOT 576            // 512 k-cols + 64 v-cols
#define SPLITQ 32
// qgemm LDS (unchanged from R3 working version)
#define LDS_K 40
#define BUFH (128 * LDS_K)

typedef _Float16 f16x8 __attribute__((ext_vector_type(8)));
typedef _Float16 f16x4 __attribute__((ext_vector_type(4)));
typedef _Float16 f16x2 __attribute__((ext_vector_type(2)));
typedef __fp16 h16x2 __attribute__((ext_vector_type(2)));   // cvt_pkrtz return type
typedef float f32x4 __attribute__((ext_vector_type(4)));

#define VMCNT(n) asm volatile("s_waitcnt vmcnt(" #n ")" ::: "memory")
#define LGKM0    asm volatile("s_waitcnt lgkmcnt(0)" ::: "memory")
#define BAR()    __builtin_amdgcn_s_barrier()
#define SCHED0() __builtin_amdgcn_sched_barrier(0)

__device__ __forceinline__ void gload16(const void* g, void* l) {
    __builtin_amdgcn_global_load_lds(
        (const __attribute__((address_space(1))) void*)g,
        (__attribute__((address_space(3))) void*)l, 16, 0, 0);
}

// ---------------- prep: Wt[n][k] = (f16) {Wk|Wv}[k][n]; bb = {bk|bv} -------
__global__ __launch_bounds__(256) void prep(const float* __restrict__ Wk,
                                            const float* __restrict__ Wv,
                                            const float* __restrict__ bk,
                                            const float* __restrict__ bv,
                                            _Float16* __restrict__ Wt,
                                            float* __restrict__ bb)
{
    __shared__ float td[64][65];
    const int kt = blockIdx.x;      // 0..31
    const int nt = blockIdx.y;      // 0..8 (8 == Wv tile)
    const int k0 = kt * 64;
    const bool isv = (nt == 8);
    const float* src = isv ? Wv : Wk;
    const int ldsrc = isv ? DV_ : HID_;
    const int ncol0 = isv ? 0 : nt * 64;
    for (int e = threadIdx.x; e < 4096; e += 256) {
        const int ki = e >> 6, ni = e & 63;
        td[ki][ni] = src[(size_t)(k0 + ki) * ldsrc + ncol0 + ni];
    }
    __syncthreads();
    for (int e = threadIdx.x; e < 4096; e += 256) {
        const int ni = e >> 6, ki = e & 63;
        Wt[(size_t)(nt * 64 + ni) * TAU_ + k0 + ki] = (_Float16)td[ki][ni];
    }
    if (kt == 0 && threadIdx.x < 64) {
        const int ng = nt * 64 + threadIdx.x;
        bb[ng] = isv ? bv[threadIdx.x] : bk[ng];
    }
}

// ---------------- qgemm: unchanged R3 128x128 split-K tile -----------------
__device__ __forceinline__ void gemm_tile128(
    _Float16* __restrict__ As, _Float16* __restrict__ Bs,
    const float* __restrict__ Ag, int lda,
    const float* __restrict__ Bg, int ldb,
    _Float16* __restrict__ Cg, int ldc, int K)
{
    const int tid = threadIdx.x;
    const int lane = tid & 63;
    const int wid = tid >> 6;
    const int wr = wid >> 1;
    const int wc = wid & 1;
    const int am = tid >> 1;
    const int ak = (tid & 1) << 4;
    const int btn = tid & 31;
    const int btk = tid >> 5;
    const int arow = wr * 64 + (lane & 15);
    const int brow = wc * 64 + (lane & 15);
    const int kblk = (lane >> 4) << 3;

    f32x4 acc[4][4];
#pragma unroll
    for (int mi = 0; mi < 4; ++mi)
#pragma unroll
        for (int ni = 0; ni < 4; ++ni)
            acc[mi][ni] = (f32x4){0.f, 0.f, 0.f, 0.f};

    float4 rA[8], rB[8];
    const int nt = K >> 5;

    auto load_stage = [&](float4 (&r)[8], int ks) {
        const float* ap = Ag + (size_t)am * lda + ks + ak;
#pragma unroll
        for (int i = 0; i < 4; ++i) r[i] = *(const float4*)(ap + 4 * i);
        const float* bp = Bg + (size_t)(ks + btk * 4) * ldb + btn * 4;
#pragma unroll
        for (int i = 0; i < 4; ++i) r[4 + i] = *(const float4*)(bp + (size_t)i * ldb);
    };
    auto write_stage = [&](float4 (&r)[8], int buf) {
        _Float16* abase = As + buf * BUFH + am * LDS_K + ak;
        const float* fa = (const float*)&r[0];
        f16x8 h0, h1;
#pragma unroll
        for (int i = 0; i < 8; ++i) { h0[i] = (_Float16)fa[i]; h1[i] = (_Float16)fa[8 + i]; }
        *(f16x8*)abase = h0;
        *(f16x8*)(abase + 8) = h1;
        const float* fb = (const float*)&r[4];
#pragma unroll
        for (int j = 0; j < 4; ++j) {
            f16x4 w;
#pragma unroll
            for (int i = 0; i < 4; ++i) w[i] = (_Float16)fb[i * 4 + j];
            *(f16x4*)(Bs + buf * BUFH + (btn * 4 + j) * LDS_K + btk * 4) = w;
        }
    };
    auto compute = [&](int buf) {
        const _Float16* ab = As + buf * BUFH;
        const _Float16* bbp = Bs + buf * BUFH;
        f16x8 af[4], bf[4];
#pragma unroll
        for (int mi = 0; mi < 4; ++mi)
            af[mi] = *(const f16x8*)(ab + (arow + mi * 16) * LDS_K + kblk);
#pragma unroll
        for (int ni = 0; ni < 4; ++ni)
            bf[ni] = *(const f16x8*)(bbp + (brow + ni * 16) * LDS_K + kblk);
#pragma unroll
        for (int mi = 0; mi < 4; ++mi)
#pragma unroll
            for (int ni = 0; ni < 4; ++ni)
                acc[mi][ni] = __builtin_amdgcn_mfma_f32_16x16x32_f16(
                    af[mi], bf[ni], acc[mi][ni], 0, 0, 0);
    };

    load_stage(rA, 0);
    load_stage(rB, 32);
    write_stage(rA, 0);
    __syncthreads();
    for (int t = 0; t < nt; t += 2) {
        if (t + 2 < nt) load_stage(rA, (t + 2) << 5);
        compute(0);
        if (t + 1 < nt) write_stage(rB, 1);
        __syncthreads();
        if (t + 3 < nt) load_stage(rB, (t + 3) << 5);
        compute(1);
        if (t + 2 < nt) write_stage(rA, 0);
        __syncthreads();
    }
#pragma unroll
    for (int mi = 0; mi < 4; ++mi)
#pragma unroll
        for (int ni = 0; ni < 4; ++ni) {
            const int row = wr * 64 + mi * 16 + ((lane >> 4) << 2);
            const int col = wc * 64 + ni * 16 + (lane & 15);
#pragma unroll
            for (int r = 0; r < 4; ++r)
                Cg[(size_t)(row + r) * ldc + col] = (_Float16)acc[mi][ni][r];
        }
}

__global__ __launch_bounds__(256, 2) void qgemm(const float* __restrict__ X,
                                                const float* __restrict__ Wq,
                                                _Float16* __restrict__ qpart)
{
    __shared__ __align__(16) _Float16 smem[4 * BUFH];
    const int b = blockIdx.x;
    const int w = (b & 7) * 64 + (b >> 3);
    const int s = w >> 4;
    const int bm = (w >> 2) & 3;
    const int bn = w & 3;
    const int KS = MSG_ / SPLITQ;  // 1024
    gemm_tile128(smem, smem + 2 * BUFH,
                 X + (size_t)bm * 128 * MSG_ + s * KS, MSG_,
                 Wq + (size_t)(s * KS) * HID_ + bn * 128, HID_,
                 qpart + (size_t)s * (N_AG * HID_) + bm * 128 * HID_ + bn * 128, HID_,
                 KS);
}

// ---------------- kvgemm v2: 64x192 tile, swizzled LDS, counted vmcnt ------
// A [8192 x 2048] f32 (reg-staged -> fp16, XOR-swizzled ds_write_b128)
// B = Wt [576 x 2048] f16 (global_load_lds, source pre-swizzled)
// C = cmat [8192 x 576] f16 (+bias)
__global__ __launch_bounds__(256, 2) void kvgemm(const float* __restrict__ A,
                                                 const _Float16* __restrict__ Wt,
                                                 const float* __restrict__ bb,
                                                 _Float16* __restrict__ cmat)
{
    // LDS: Abuf0 @0 (4KB), Abuf1 @4K, Bbuf0 @8K (12KB), Bbuf1 @20K
    __shared__ __align__(1024) char smem[32768];
    const int tid = threadIdx.x;
    const int l = tid & 63;
    const int w = tid >> 6;        // wave 0..3 (1x4 col grid)

    const int b = blockIdx.x;
    const int wsw = (b & 7) * 48 + (b >> 3);   // 384 = 8 XCD chunks of 48
    const int bm = wsw / 3;
    const int bn = wsw % 3;
    const int m0 = bm * 64;
    const int n0 = bn * 192;

    // A staging: thread -> (row=tid>>2, global chunk tid&3 of 8 floats)
    const int arow = tid >> 2;
    const int aslot = (tid & 3) ^ ((tid >> 3) & 3);   // XOR swizzle
    const float* ag = A + (size_t)(m0 + arow) * TAU_ + (tid & 3) * 8;
    char* const alds = smem + arow * 64 + aslot * 16;

    // B dma: source chunk pre-swizzled so linear LDS ends up swizzled
    const int bsrcc = (l & 3) ^ ((l >> 3) & 3);

    // compute-side constants
    const int r15 = l & 15;
    const int swz = ((l >> 4) ^ ((r15 >> 1) & 3)) * 16;

    f32x4 acc[4][3];
#pragma unroll
    for (int mi = 0; mi < 4; ++mi)
#pragma unroll
        for (int ni = 0; ni < 3; ++ni)
            acc[mi][ni] = (f32x4){0.f, 0.f, 0.f, 0.f};

    float4 r0[2], r1[2];

    auto aload = [&](float4 (&r)[2], int t) {
        const float* p = ag + t * 32;
        r[0] = *(const float4*)(p);
        r[1] = *(const float4*)(p + 4);
    };
    auto awrite = [&](float4 (&r)[2], int parity) {
        union { h16x2 h2[4]; f16x8 v; } u;
        const float* f = (const float*)&r[0];
        u.h2[0] = __builtin_amdgcn_cvt_pkrtz(f[0], f[1]);
        u.h2[1] = __builtin_amdgcn_cvt_pkrtz(f[2], f[3]);
        u.h2[2] = __builtin_amdgcn_cvt_pkrtz(f[4], f[5]);
        u.h2[3] = __builtin_amdgcn_cvt_pkrtz(f[6], f[7]);
        *(f16x8*)(alds + parity * 4096) = u.v;
    };
    auto bdma = [&](int t, int parity) {
        char* base = smem + 8192 + parity * 12288;
#pragma unroll
        for (int jj = 0; jj < 3; ++jj) {
            const int j = w * 3 + jj;
            const int row = 16 * j + (l >> 2);
            const _Float16* gp = Wt + (size_t)(n0 + row) * TAU_ + t * 32 + bsrcc * 8;
            gload16(gp, base + j * 1024);
        }
    };
    auto compute = [&](int parity) {
        const char* ab = smem + parity * 4096;
        const char* bbp = smem + 8192 + parity * 12288;
        f16x8 af[4], bf[3];
#pragma unroll
        for (int mi = 0; mi < 4; ++mi)
            af[mi] = *(const f16x8*)(ab + (mi * 16 + r15) * 64 + swz);
#pragma unroll
        for (int ni = 0; ni < 3; ++ni)
            bf[ni] = *(const f16x8*)(bbp + (w * 48 + ni * 16 + r15) * 64 + swz);
        __builtin_amdgcn_s_setprio(1);
#pragma unroll
        for (int mi = 0; mi < 4; ++mi)
#pragma unroll
            for (int ni = 0; ni < 3; ++ni)
                acc[mi][ni] = __builtin_amdgcn_mfma_f32_16x16x32_f16(
                    af[mi], bf[ni], acc[mi][ni], 0, 0, 0);
        __builtin_amdgcn_s_setprio(0);
    };

    // prologue: two tiles in flight; vmcnt(5) = leave {B(3),A(2)} of next tile outstanding
    bdma(0, 0); aload(r0, 0);
    bdma(1, 1); aload(r1, 1);
    VMCNT(5);
    awrite(r0, 0);
    LGKM0;

    for (int t = 0; t < 62; t += 2) {
        BAR(); SCHED0();
        compute(0);
        SCHED0(); BAR();
        bdma(t + 2, 0); aload(r0, t + 2);
        VMCNT(5);
        awrite(r1, 1);
        LGKM0;

        BAR(); SCHED0();
        compute(1);
        SCHED0(); BAR();
        bdma(t + 3, 1); aload(r1, t + 3);
        VMCNT(5);
        awrite(r0, 0);
        LGKM0;
    }
    // t = 62
    BAR(); SCHED0();
    compute(0);
    SCHED0(); BAR();
    VMCNT(0);
    awrite(r1, 1);
    LGKM0;
    // t = 63
    BAR(); SCHED0();
    compute(1);

    // epilogue: C/D layout col=lane&15, row=(lane>>4)*4+r
#pragma unroll
    for (int mi = 0; mi < 4; ++mi)
#pragma unroll
        for (int ni = 0; ni < 3; ++ni) {
            const int row = m0 + mi * 16 + ((l >> 4) << 2);
            const int col = n0 + w * 48 + ni * 16 + r15;
            const float badd = bb[col];
#pragma unroll
            for (int r = 0; r < 4; ++r)
                cmat[(size_t)(row + r) * NTOT + col] = (_Float16)(acc[mi][ni][r] + badd);
        }
}

// ---------------- attn: q-reduce, 16 dots, softmax, PV ---------------------
__global__ __launch_bounds__(256) void attn(const _Float16* __restrict__ qpart,
                                            const _Float16* __restrict__ cmat,
                                            const float* __restrict__ bq,
                                            const float* __restrict__ bv,
                                            float* __restrict__ out)
{
    const int n = blockIdx.x;
    const int tid = threadIdx.x;
    __shared__ float qs[HID_];
    __shared__ float scr[TRAJ];

    {
        const int h2 = tid * 2;
        float a0 = bq[h2], a1 = bq[h2 + 1];
#pragma unroll
        for (int s = 0; s < SPLITQ; ++s) {
            f16x2 p = *(const f16x2*)(qpart + (size_t)s * (N_AG * HID_) + n * HID_ + h2);
            a0 += (float)p[0];
            a1 += (float)p[1];
        }
        qs[h2] = a0;
        qs[h2 + 1] = a1;
    }
    __syncthreads();

    const int w = tid >> 6;
    const int lane = tid & 63;
#pragma unroll
    for (int tt = 0; tt < 4; ++tt) {
        const int t = w * 4 + tt;
        const _Float16* kr = cmat + (size_t)(t * N_AG + n) * NTOT;
        const int h0 = lane * 8;
        f16x8 kv = *(const f16x8*)(kr + h0);
        float p = 0.f;
#pragma unroll
        for (int i = 0; i < 8; ++i) p += qs[h0 + i] * (float)kv[i];
#pragma unroll
        for (int off = 32; off > 0; off >>= 1) p += __shfl_xor(p, off);
        if (lane == 0) scr[t] = p;
    }
    __syncthreads();

    const float inv = 0.04419417382415922f;  // 1/sqrt(512)
    float sv[TRAJ];
    float mx = -1e30f;
#pragma unroll
    for (int t = 0; t < TRAJ; ++t) { sv[t] = scr[t] * inv; mx = fmaxf(mx, sv[t]); }
    float ssum = 0.f;
#pragma unroll
    for (int t = 0; t < TRAJ; ++t) { sv[t] = expf(sv[t] - mx); ssum += sv[t]; }
    const float rs = 1.f / ssum;

    if (tid < DV_) {
        float o = bv[tid];
#pragma unroll
        for (int t = 0; t < TRAJ; ++t)
            o += sv[t] * rs * (float)cmat[(size_t)(t * N_AG + n) * NTOT + HID_ + tid];
        out[n * DV_ + tid] = o;
    }
}

extern "C" void kernel_launch(void* const* d_in, const int* in_sizes, int n_in,
                              void* d_out, int out_size, void* d_ws, size_t ws_size,
                              hipStream_t stream)
{
    const float* traj = (const float*)d_in[0];  // [16,512,2048] == taus [8192,2048]
    const float* msgs = (const float*)d_in[1];  // [512, 32768]
    const float* Wq   = (const float*)d_in[2];  // [32768, 512]
    const float* bq   = (const float*)d_in[3];  // [512]
    const float* Wk   = (const float*)d_in[4];  // [2048, 512]
    const float* bk   = (const float*)d_in[5];  // [512]
    const float* Wv   = (const float*)d_in[6];  // [2048, 64]
    const float* bv   = (const float*)d_in[7];  // [64]
    float* out = (float*)d_out;                 // [512, 64]

    // ws (28.6 MB; R1 proved >=34 MB available):
    // qpart f16 [32][512][512] | cmat f16 [8192][576] | Wt f16 [576][2048] | bb f32 [576]
    _Float16* qpart = (_Float16*)d_ws;
    _Float16* cmat  = qpart + (size_t)SPLITQ * N_AG * HID_;
    _Float16* Wt    = cmat + (size_t)TRAJ * N_AG * NTOT;
    float*    bb    = (float*)(Wt + (size_t)NTOT * TAU_);

    prep<<<dim3(32, 9), 256, 0, stream>>>(Wk, Wv, bk, bv, Wt, bb);
    qgemm<<<512, 256, 0, stream>>>(msgs, Wq, qpart);
    kvgemm<<<384, 256, 0, stream>>>(traj, Wt, bb, cmat);
    attn<<<512, 256, 0, stream>>>(qpart, cmat, bq, bv, out);
}